// Round 1
// baseline (76.411 us; speedup 1.0000x reference)
//
#include <hip/hip_runtime.h>

#define BS 8
#define B2 16
#define S 2048
#define H 2048
#define PAD_ID 0

constexpr int BLOCKS_PER_BATCH = 32;
constexpr int WAVES_PER_BLOCK = 4;
constexpr int ROWS_PER_WAVE = S / (BLOCKS_PER_BATCH * WAVES_PER_BLOCK); // 16

// rewards[b][s] = sum_d hidden[b][s][d] * emb[risk_type[b%8]][d] * v_w[d]
__global__ __launch_bounds__(256) void rewards_kernel(
    const float* __restrict__ hidden,    // [B2, S, H]
    const int*   __restrict__ risk_type, // [BS]
    const float* __restrict__ emb,       // [N_RISK, H]
    const float* __restrict__ v_w,       // [H]
    float* __restrict__ rewards)         // [B2, S]
{
    const int b    = blockIdx.x / BLOCKS_PER_BATCH;
    const int blk  = blockIdx.x % BLOCKS_PER_BATCH;
    const int wave = threadIdx.x >> 6;
    const int lane = threadIdx.x & 63;
    const int rt   = risk_type[b & 7]; // b % 8 (risk_double = concat(risk_emb, risk_emb))

    // Per-lane combined weights: lane covers float4 index c*64+lane, c=0..7.
    float4 w[8];
    const float4* embv = (const float4*)(emb + (size_t)rt * H);
    const float4* vwv  = (const float4*)v_w;
#pragma unroll
    for (int c = 0; c < 8; ++c) {
        int idx = c * 64 + lane;
        float4 e = embv[idx];
        float4 v = vwv[idx];
        w[c] = make_float4(e.x * v.x, e.y * v.y, e.z * v.z, e.w * v.w);
    }

    const int row0 = (blk * WAVES_PER_BLOCK + wave) * ROWS_PER_WAVE;
    const float4* hb = (const float4*)(hidden + (size_t)b * S * H);

    for (int r = 0; r < ROWS_PER_WAVE; ++r) {
        int s = row0 + r;
        const float4* hr = hb + (size_t)s * (H / 4);
        float acc = 0.f;
#pragma unroll
        for (int c = 0; c < 8; ++c) {
            float4 h = hr[c * 64 + lane];
            acc += h.x * w[c].x + h.y * w[c].y + h.z * w[c].z + h.w * w[c].w;
        }
#pragma unroll
        for (int off = 32; off > 0; off >>= 1)
            acc += __shfl_xor(acc, off, 64);
        if (lane == 0) rewards[b * S + s] = acc;
    }
}

// One block per example b in [0, BS)
__global__ __launch_bounds__(256) void finalize_kernel(
    const int*   __restrict__ input_ids, // [B2, S]
    const float* __restrict__ unsafe,    // [BS]
    const float* __restrict__ rewards,   // [B2, S]
    float* __restrict__ per_ex,          // [BS] (ws)
    float* __restrict__ out)             // [17]
{
    const int b   = blockIdx.x;
    const int tid = threadIdx.x;
    const int* cid = input_ids + b * S;
    const int* rid = input_ids + (b + BS) * S;

    __shared__ int s_cind, s_rind, s_div;
    if (tid == 0) { s_cind = S; s_rind = S; s_div = S; }
    __syncthreads();

    int my_cind = S, my_rind = S, my_div = S;
    for (int s = tid; s < S; s += 256) {
        int c = cid[s], r = rid[s];
        if (c == PAD_ID && s < my_cind) my_cind = s;
        if (r == PAD_ID && s < my_rind) my_rind = s;
        if (c != r      && s < my_div)  my_div  = s;
    }
    atomicMin(&s_cind, my_cind);
    atomicMin(&s_rind, my_rind);
    atomicMin(&s_div,  my_div);
    __syncthreads();

    const int c_ind     = s_cind;
    const int r_ind_pad = s_rind;
    const bool has_div  = (s_div < S);
    const int div   = has_div ? s_div : (S - 1);
    const int end   = has_div ? max(c_ind, r_ind_pad) : S;
    const int r_ind = has_div ? r_ind_pad : c_ind;

    const float u = unsafe[b];
    const float* c_rew = rewards + b * S;
    const float* r_rew = rewards + (b + BS) * S;

    float sum = 0.f;
    for (int s = div + tid; s < end; s += 256) {
        float h = u - (c_rew[s] - r_rew[s]);
        sum += (h > 0.f) ? h : 0.f;
    }

    __shared__ float s_red[256];
    s_red[tid] = sum;
    __syncthreads();
    for (int off = 128; off > 0; off >>= 1) {
        if (tid < off) s_red[tid] += s_red[tid + off];
        __syncthreads();
    }

    if (tid == 0) {
        float cnt = (float)max(end - div, 1);
        per_ex[b]   = s_red[0] / cnt;
        out[1 + b]  = c_rew[c_ind - 1];
        out[9 + b]  = r_rew[r_ind - 1];
    }
}

__global__ void loss_kernel(const float* __restrict__ per_ex,
                            float* __restrict__ out)
{
    if (threadIdx.x == 0) {
        float s = 0.f;
        for (int i = 0; i < BS; ++i) s += per_ex[i];
        out[0] = s / (float)BS;
    }
}

extern "C" void kernel_launch(void* const* d_in, const int* in_sizes, int n_in,
                              void* d_out, int out_size, void* d_ws, size_t ws_size,
                              hipStream_t stream) {
    const float* hidden    = (const float*)d_in[0];
    const int*   input_ids = (const int*)d_in[1];
    const float* unsafe    = (const float*)d_in[2];
    const int*   risk_type = (const int*)d_in[3];
    const float* emb       = (const float*)d_in[4];
    const float* v_w       = (const float*)d_in[5];
    float* out = (float*)d_out;

    float* rewards = (float*)d_ws;          // B2*S floats = 128 KiB
    float* per_ex  = rewards + B2 * S;      // BS floats

    rewards_kernel<<<B2 * BLOCKS_PER_BATCH, 256, 0, stream>>>(
        hidden, risk_type, emb, v_w, rewards);
    finalize_kernel<<<BS, 256, 0, stream>>>(
        input_ids, unsafe, rewards, per_ex, out);
    loss_kernel<<<1, 64, 0, stream>>>(per_ex, out);
}

// Round 2
// 62.535 us; speedup vs baseline: 1.2219x; 1.2219x over previous
//
#include <hip/hip_runtime.h>

#define BS 8
#define B2 16
#define S 2048
#define H 2048
#define PAD_ID 0

constexpr int BLOCKS_PER_BATCH = 128;
constexpr int WAVES_PER_BLOCK = 4;
constexpr int ROWS_PER_WAVE = S / (BLOCKS_PER_BATCH * WAVES_PER_BLOCK); // 4

// rewards[b][s] = sum_d hidden[b][s][d] * emb[risk_type[b%8]][d] * v_w[d]
__global__ __launch_bounds__(256) void rewards_kernel(
    const float* __restrict__ hidden,    // [B2, S, H]
    const int*   __restrict__ risk_type, // [BS]
    const float* __restrict__ emb,       // [N_RISK, H]
    const float* __restrict__ v_w,       // [H]
    float* __restrict__ rewards)         // [B2, S]
{
    const int b    = blockIdx.x / BLOCKS_PER_BATCH;
    const int blk  = blockIdx.x % BLOCKS_PER_BATCH;
    const int wave = threadIdx.x >> 6;
    const int lane = threadIdx.x & 63;
    const int rt   = risk_type[b & 7]; // risk_double = concat(risk_emb, risk_emb)

    // Per-lane combined weights: lane covers float4 index c*64+lane, c=0..7.
    // emb row (8KB) + v_w (8KB) stay L1-resident -> negligible HBM traffic.
    float4 w[8];
    const float4* embv = (const float4*)(emb + (size_t)rt * H);
    const float4* vwv  = (const float4*)v_w;
#pragma unroll
    for (int c = 0; c < 8; ++c) {
        int idx = c * 64 + lane;
        float4 e = embv[idx];
        float4 v = vwv[idx];
        w[c] = make_float4(e.x * v.x, e.y * v.y, e.z * v.z, e.w * v.w);
    }

    const int row0 = (blk * WAVES_PER_BLOCK + wave) * ROWS_PER_WAVE;
    const float4* hb = (const float4*)(hidden + (size_t)b * S * H);

    // Two rows in flight per iteration: 16 independent float4 loads before
    // any dependent reduction.
#pragma unroll
    for (int r = 0; r < ROWS_PER_WAVE; r += 2) {
        const int s0 = row0 + r;
        const int s1 = s0 + 1;
        const float4* hr0 = hb + (size_t)s0 * (H / 4);
        const float4* hr1 = hb + (size_t)s1 * (H / 4);
        float acc0 = 0.f, acc1 = 0.f;
#pragma unroll
        for (int c = 0; c < 8; ++c) {
            float4 h0 = hr0[c * 64 + lane];
            float4 h1 = hr1[c * 64 + lane];
            acc0 += h0.x * w[c].x + h0.y * w[c].y + h0.z * w[c].z + h0.w * w[c].w;
            acc1 += h1.x * w[c].x + h1.y * w[c].y + h1.z * w[c].z + h1.w * w[c].w;
        }
#pragma unroll
        for (int off = 32; off > 0; off >>= 1) {
            acc0 += __shfl_xor(acc0, off, 64);
            acc1 += __shfl_xor(acc1, off, 64);
        }
        if (lane == 0) {
            rewards[b * S + s0] = acc0;
            rewards[b * S + s1] = acc1;
        }
    }
}

// Single block, 8 waves: wave b handles example b. Computes per-example
// indices, hinge mean, scores, and the final loss (deterministic order).
__global__ __launch_bounds__(512) void finalize_kernel(
    const int*   __restrict__ input_ids, // [B2, S]
    const float* __restrict__ unsafe,    // [BS]
    const float* __restrict__ rewards,   // [B2, S]
    float* __restrict__ out)             // [17]
{
    const int b    = threadIdx.x >> 6;
    const int lane = threadIdx.x & 63;
    const int* cid = input_ids + b * S;
    const int* rid = input_ids + (b + BS) * S;

    int my_cind = S, my_rind = S, my_div = S;
    for (int s = lane; s < S; s += 64) {
        int c = cid[s], r = rid[s];
        if (c == PAD_ID && s < my_cind) my_cind = s;
        if (r == PAD_ID && s < my_rind) my_rind = s;
        if (c != r      && s < my_div)  my_div  = s;
    }
#pragma unroll
    for (int off = 32; off > 0; off >>= 1) {
        my_cind = min(my_cind, __shfl_xor(my_cind, off, 64));
        my_rind = min(my_rind, __shfl_xor(my_rind, off, 64));
        my_div  = min(my_div,  __shfl_xor(my_div,  off, 64));
    }

    const int c_ind     = my_cind;
    const int r_ind_pad = my_rind;
    const bool has_div  = (my_div < S);
    const int div   = has_div ? my_div : (S - 1);
    const int end   = has_div ? max(c_ind, r_ind_pad) : S;
    const int r_ind = has_div ? r_ind_pad : c_ind;

    const float u = unsafe[b];
    const float* c_rew = rewards + b * S;
    const float* r_rew = rewards + (b + BS) * S;

    float sum = 0.f;
    for (int s = div + lane; s < end; s += 64) {
        float h = u - (c_rew[s] - r_rew[s]);
        sum += (h > 0.f) ? h : 0.f;
    }
#pragma unroll
    for (int off = 32; off > 0; off >>= 1)
        sum += __shfl_xor(sum, off, 64);

    __shared__ float s_per[BS];
    if (lane == 0) {
        float cnt = (float)max(end - div, 1);
        s_per[b]   = sum / cnt;
        out[1 + b] = c_rew[c_ind - 1];
        out[9 + b] = r_rew[r_ind - 1];
    }
    __syncthreads();
    if (threadIdx.x == 0) {
        float t = 0.f;
#pragma unroll
        for (int i = 0; i < BS; ++i) t += s_per[i];
        out[0] = t / (float)BS;
    }
}

extern "C" void kernel_launch(void* const* d_in, const int* in_sizes, int n_in,
                              void* d_out, int out_size, void* d_ws, size_t ws_size,
                              hipStream_t stream) {
    const float* hidden    = (const float*)d_in[0];
    const int*   input_ids = (const int*)d_in[1];
    const float* unsafe    = (const float*)d_in[2];
    const int*   risk_type = (const int*)d_in[3];
    const float* emb       = (const float*)d_in[4];
    const float* v_w       = (const float*)d_in[5];
    float* out = (float*)d_out;

    float* rewards = (float*)d_ws; // B2*S floats = 128 KiB

    rewards_kernel<<<B2 * BLOCKS_PER_BATCH, 256, 0, stream>>>(
        hidden, risk_type, emb, v_w, rewards);
    finalize_kernel<<<1, 512, 0, stream>>>(
        input_ids, unsafe, rewards, out);
}

// Round 3
// 51.848 us; speedup vs baseline: 1.4738x; 1.2061x over previous
//
#include <hip/hip_runtime.h>

#define BS 8
#define B2 16
#define S 2048
#define H 2048
#define PAD_ID 0

constexpr int BLOCKS_PER_PAIR = 128;          // s-chunks per example pair
constexpr int WAVES_PER_BLOCK = 4;
constexpr int S_PER_WAVE = S / (BLOCKS_PER_PAIR * WAVES_PER_BLOCK); // 4

// ws layout:
//   int   idx[BS*4]        : c_ind, r_ind, div, end  per example
//   float partial[BS*128]  : per-block hinge partial sums
struct WsIdx { int c_ind, r_ind, div, end; };

// ---- Kernel 1: index scan (ids only) --------------------------------------
__global__ __launch_bounds__(256) void scan_kernel(
    const int* __restrict__ input_ids,  // [B2, S]
    int* __restrict__ idx)              // [BS*4]
{
    const int b    = blockIdx.x;
    const int tid  = threadIdx.x;
    const int wave = tid >> 6;
    const int lane = tid & 63;
    const int* cid = input_ids + b * S;
    const int* rid = input_ids + (b + BS) * S;

    int my_cind = S, my_rind = S, my_div = S;
    for (int s = tid; s < S; s += 256) {
        int c = cid[s], r = rid[s];
        if (c == PAD_ID && s < my_cind) my_cind = s;
        if (r == PAD_ID && s < my_rind) my_rind = s;
        if (c != r      && s < my_div)  my_div  = s;
    }
#pragma unroll
    for (int off = 32; off > 0; off >>= 1) {
        my_cind = min(my_cind, __shfl_xor(my_cind, off, 64));
        my_rind = min(my_rind, __shfl_xor(my_rind, off, 64));
        my_div  = min(my_div,  __shfl_xor(my_div,  off, 64));
    }
    __shared__ int s_c[4], s_r[4], s_d[4];
    if (lane == 0) { s_c[wave] = my_cind; s_r[wave] = my_rind; s_d[wave] = my_div; }
    __syncthreads();
    if (tid == 0) {
        int c_ind = min(min(s_c[0], s_c[1]), min(s_c[2], s_c[3]));
        int r_pad = min(min(s_r[0], s_r[1]), min(s_r[2], s_r[3]));
        int dv    = min(min(s_d[0], s_d[1]), min(s_d[2], s_d[3]));
        bool has_div = (dv < S);
        idx[b * 4 + 0] = c_ind;
        idx[b * 4 + 1] = has_div ? r_pad : c_ind;
        idx[b * 4 + 2] = has_div ? dv : (S - 1);
        idx[b * 4 + 3] = has_div ? max(c_ind, r_pad) : S;
    }
}

// ---- Kernel 2: paired dot products + fused hinge --------------------------
__global__ __launch_bounds__(256) void main_kernel(
    const float* __restrict__ hidden,    // [B2, S, H]
    const int*   __restrict__ risk_type, // [BS]
    const float* __restrict__ emb,       // [N_RISK, H]
    const float* __restrict__ v_w,       // [H]
    const float* __restrict__ unsafe,    // [BS]
    const int*   __restrict__ idx,       // [BS*4]
    float* __restrict__ partial,         // [BS*128]
    float* __restrict__ out)             // [17]
{
    const int b    = blockIdx.x / BLOCKS_PER_PAIR;
    const int blk  = blockIdx.x % BLOCKS_PER_PAIR;
    const int wave = threadIdx.x >> 6;
    const int lane = threadIdx.x & 63;
    const int rt   = risk_type[b];

    // Combined per-lane weights (emb row + v_w stay L1/L2-resident).
    float4 w[8];
    const float4* embv = (const float4*)(emb + (size_t)rt * H);
    const float4* vwv  = (const float4*)v_w;
#pragma unroll
    for (int c = 0; c < 8; ++c) {
        int i = c * 64 + lane;
        float4 e = embv[i];
        float4 v = vwv[i];
        w[c] = make_float4(e.x * v.x, e.y * v.y, e.z * v.z, e.w * v.w);
    }

    const int c_ind = idx[b * 4 + 0];
    const int r_ind = idx[b * 4 + 1];
    const int dv    = idx[b * 4 + 2];
    const int end   = idx[b * 4 + 3];
    const float u   = unsafe[b];

    const float4* hc = (const float4*)(hidden + (size_t)b * S * H);
    const float4* hr = (const float4*)(hidden + (size_t)(b + BS) * S * H);

    const int s0 = (blk * WAVES_PER_BLOCK + wave) * S_PER_WAVE;
    float hinge = 0.f;

#pragma unroll
    for (int r = 0; r < S_PER_WAVE; ++r) {
        const int s = s0 + r;
        const float4* rc = hc + (size_t)s * (H / 4);
        const float4* rr = hr + (size_t)s * (H / 4);
        float ac = 0.f, ar = 0.f;
#pragma unroll
        for (int c = 0; c < 8; ++c) {
            float4 x = rc[c * 64 + lane];
            float4 y = rr[c * 64 + lane];
            ac += x.x * w[c].x + x.y * w[c].y + x.z * w[c].z + x.w * w[c].w;
            ar += y.x * w[c].x + y.y * w[c].y + y.z * w[c].z + y.w * w[c].w;
        }
#pragma unroll
        for (int off = 32; off > 0; off >>= 1) {
            ac += __shfl_xor(ac, off, 64);
            ar += __shfl_xor(ar, off, 64);
        }
        if (lane == 0) {
            if (s >= dv && s < end) {
                float h = u - (ac - ar);
                hinge += (h > 0.f) ? h : 0.f;
            }
            if (s == c_ind - 1) out[1 + b] = ac;
            if (s == r_ind - 1) out[9 + b] = ar;
        }
    }

    __shared__ float s_h[WAVES_PER_BLOCK];
    if (lane == 0) s_h[wave] = hinge;
    __syncthreads();
    if (threadIdx.x == 0)
        partial[b * BLOCKS_PER_PAIR + blk] =
            (s_h[0] + s_h[1]) + (s_h[2] + s_h[3]);
}

// ---- Kernel 3: deterministic loss reduction -------------------------------
__global__ __launch_bounds__(512) void loss_kernel(
    const float* __restrict__ partial, // [BS*128]
    const int*   __restrict__ idx,     // [BS*4]
    float* __restrict__ out)           // [17]
{
    const int b    = threadIdx.x >> 6;
    const int lane = threadIdx.x & 63;
    // wave b sums its 128 partials in a fixed order
    float s = partial[b * BLOCKS_PER_PAIR + lane]
            + partial[b * BLOCKS_PER_PAIR + 64 + lane];
#pragma unroll
    for (int off = 32; off > 0; off >>= 1)
        s += __shfl_xor(s, off, 64);

    __shared__ float s_per[BS];
    if (lane == 0) {
        int cnt = max(idx[b * 4 + 3] - idx[b * 4 + 2], 1);
        s_per[b] = s / (float)cnt;
    }
    __syncthreads();
    if (threadIdx.x == 0) {
        float t = 0.f;
#pragma unroll
        for (int i = 0; i < BS; ++i) t += s_per[i];
        out[0] = t / (float)BS;
    }
}

extern "C" void kernel_launch(void* const* d_in, const int* in_sizes, int n_in,
                              void* d_out, int out_size, void* d_ws, size_t ws_size,
                              hipStream_t stream) {
    const float* hidden    = (const float*)d_in[0];
    const int*   input_ids = (const int*)d_in[1];
    const float* unsafe    = (const float*)d_in[2];
    const int*   risk_type = (const int*)d_in[3];
    const float* emb       = (const float*)d_in[4];
    const float* v_w       = (const float*)d_in[5];
    float* out = (float*)d_out;

    int*   idx     = (int*)d_ws;                 // BS*4 ints
    float* partial = (float*)((char*)d_ws + 256); // BS*128 floats

    scan_kernel<<<BS, 256, 0, stream>>>(input_ids, idx);
    main_kernel<<<BS * BLOCKS_PER_PAIR, 256, 0, stream>>>(
        hidden, risk_type, emb, v_w, unsafe, idx, partial, out);
    loss_kernel<<<1, 512, 0, stream>>>(partial, idx, out);
}